// Round 1
// baseline (147.209 us; speedup 1.0000x reference)
//
#include <hip/hip_runtime.h>

typedef __attribute__((ext_vector_type(4))) float f32x4;
typedef __attribute__((ext_vector_type(8))) short s16x8;
typedef __attribute__((ext_vector_type(4))) short s16x4;

#define BATCH 4
#define SEQ 4096
#define EMB 1024
#define HD 64

// fp32 -> bf16 round-to-nearest-even
static __device__ __forceinline__ unsigned short f2bf(float f) {
  union { float f; unsigned int u; } a;
  a.f = f;
  unsigned int u = a.u;
  u += 0x7FFFu + ((u >> 16) & 1u);
  return (unsigned short)(u >> 16);
}

// async global->LDS, 16B per lane. dst must be wave-uniform; HW adds lane*16.
#define GLL16(g, l)                                                        \
  __builtin_amdgcn_global_load_lds(                                        \
      (const __attribute__((address_space(1))) unsigned int*)(g),          \
      (__attribute__((address_space(3))) unsigned int*)(l), 16, 0, 0)

// ---------------------------------------------------------------------------
// Kernel 1: W [1024][64] fp32 (q,k,v) -> wT [192][1024] bf16 (row = out col)
// ---------------------------------------------------------------------------
__global__ __launch_bounds__(256) void k_wt(const float* __restrict__ Wq,
                                            const float* __restrict__ Wk,
                                            const float* __restrict__ Wv,
                                            unsigned short* __restrict__ wt) {
  __shared__ float lds[64][65];
  int tid = threadIdx.x;
  int which = blockIdx.x >> 4;  // 0=q 1=k 2=v
  int kt = blockIdx.x & 15;     // 64-row k tile
  const float* W = (which == 0) ? Wq : ((which == 1) ? Wk : Wv);
#pragma unroll
  for (int i = 0; i < 4; ++i) {
    int idx = i * 256 + tid;  // 1024 float4 chunks
    int row = idx >> 4, c4 = idx & 15;
    float4 v = *(const float4*)(W + (size_t)(kt * 64 + row) * 64 + c4 * 4);
    lds[row][c4 * 4 + 0] = v.x;
    lds[row][c4 * 4 + 1] = v.y;
    lds[row][c4 * 4 + 2] = v.z;
    lds[row][c4 * 4 + 3] = v.w;
  }
  __syncthreads();
#pragma unroll
  for (int i = 0; i < 2; ++i) {
    int idx = i * 256 + tid;  // 512 chunks of 8 bf16
    int n = idx >> 3, kc = idx & 7;
    s16x8 v;
#pragma unroll
    for (int j = 0; j < 8; ++j) v[j] = (short)f2bf(lds[kc * 8 + j][n]);
    *(s16x8*)(wt + ((size_t)(which * 64 + n) * 1024 + kt * 64 + kc * 8)) = v;
  }
}

// ---------------------------------------------------------------------------
// Kernel 2: fused QKV projection. M=16384 rows, N=192 cols, K=1024.
// q scaled by 1/8 (softmax scale folded in). v written transposed [B][D][T].
// ---------------------------------------------------------------------------
__global__ __launch_bounds__(256) void k_proj(const float* __restrict__ x,
                                              const unsigned short* __restrict__ wt,
                                              const float* __restrict__ bq,
                                              const float* __restrict__ bk,
                                              const float* __restrict__ bv,
                                              unsigned short* __restrict__ qws,
                                              unsigned short* __restrict__ kws,
                                              unsigned short* __restrict__ vtws) {
  __shared__ char xb[64 * 128];   // 64 rows x 64 bf16, XOR-swizzled chunks
  __shared__ char wb[192 * 128];  // 192 cols x 64 k bf16, swizzled via source
  int tid = threadIdx.x;
  int w = tid >> 6, ln = tid & 63;
  int lg = ln >> 4, lc = ln & 15;
  int m0 = blockIdx.x * 64;

  f32x4 acc[12];
#pragma unroll
  for (int i = 0; i < 12; ++i) acc[i] = (f32x4){0.f, 0.f, 0.f, 0.f};

  for (int kt = 0; kt < 16; ++kt) {
    // stage x tile (fp32 -> bf16, swizzled ds_write)
#pragma unroll
    for (int i = 0; i < 4; ++i) {
      int idx = i * 256 + tid;  // 1024 chunks of 4 floats
      int row = idx >> 4, c4 = idx & 15;
      float4 v = *(const float4*)(x + (size_t)(m0 + row) * 1024 + kt * 64 + c4 * 4);
      s16x4 h;
      h[0] = (short)f2bf(v.x);
      h[1] = (short)f2bf(v.y);
      h[2] = (short)f2bf(v.z);
      h[3] = (short)f2bf(v.w);
      int byteoff = row * 128 + ((((c4 >> 1) ^ (row & 7)) << 4) | ((c4 & 1) << 3));
      *(s16x4*)(xb + byteoff) = h;
    }
    // stage wT tile via global_load_lds, source pre-swizzled
#pragma unroll
    for (int p = 0; p < 6; ++p) {
      int idx = p * 256 + tid;
      int rr = idx >> 3, cc = idx & 7;
      const char* src = (const char*)wt + (size_t)rr * 2048 + kt * 128 + ((cc ^ (rr & 7)) << 4);
      GLL16(src, wb + (p * 256 + w * 64) * 16);
    }
    __syncthreads();

    s16x8 a[2];
#pragma unroll
    for (int kk = 0; kk < 2; ++kk) {
      int row = w * 16 + lc;
      int ch = (kk * 4 + lg) ^ (row & 7);
      a[kk] = *(const s16x8*)(xb + row * 128 + ch * 16);
    }
#pragma unroll
    for (int cf = 0; cf < 12; ++cf) {
#pragma unroll
      for (int kk = 0; kk < 2; ++kk) {
        int rowb = cf * 16 + lc;
        int ch = (kk * 4 + lg) ^ (rowb & 7);
        s16x8 bfr = *(const s16x8*)(wb + rowb * 128 + ch * 16);
        acc[cf] = __builtin_amdgcn_mfma_f32_16x16x32_bf16(a[kk], bfr, acc[cf], 0, 0, 0);
      }
    }
    __syncthreads();
  }

  // epilogue: C layout col=lane&15, row=(lane>>4)*4+r
#pragma unroll
  for (int cf = 0; cf < 12; ++cf) {
    int dcol = (cf & 3) * 16 + lc;
    float bias = (cf < 4) ? bq[dcol] : ((cf < 8) ? bk[dcol] : bv[dcol]);
#pragma unroll
    for (int r = 0; r < 4; ++r) {
      int grow = m0 + w * 16 + lg * 4 + r;  // global row in [0,16384)
      float val = acc[cf][r] + bias;
      if (cf < 4) {
        qws[(size_t)grow * 64 + dcol] = f2bf(val * 0.125f);
      } else if (cf < 8) {
        kws[(size_t)grow * 64 + dcol] = f2bf(val);
      } else {
        int b = grow >> 12, t = grow & 4095;
        vtws[(size_t)(b * 64 + dcol) * SEQ + t] = f2bf(val);
      }
    }
  }
}

// ---------------------------------------------------------------------------
// Kernel 3: flash attention. Block = (qt, b), 4 waves x 16 q-rows (QB=64).
// K tiles [64 k][64 d], V tiles as Vt [64 d][64 k], both XOR-swizzled in LDS.
// Double-buffered global_load_lds with counted vmcnt.
// ---------------------------------------------------------------------------
__global__ __launch_bounds__(256) void k_attn(const unsigned short* __restrict__ qws,
                                              const unsigned short* __restrict__ kws,
                                              const unsigned short* __restrict__ vtws,
                                              float* __restrict__ out) {
  __shared__ char Kb[2][8192];
  __shared__ char Vb[2][8192];
  __shared__ char Pb[4][2304];  // per-wave P, 16 rows x 72 bf16 (pad -> 2-way)
  int tid = threadIdx.x;
  int w = tid >> 6, ln = tid & 63;
  int lg = ln >> 4, lc = ln & 15;
  int qt = blockIdx.x, b = blockIdx.y;

  const char* kbase = (const char*)(kws + (size_t)b * SEQ * 64);
  const char* vbase = (const char*)(vtws + (size_t)b * 64 * SEQ);

  // Q fragments (scale already folded into q by k_proj)
  s16x8 qa[2];
  {
    int trow = qt * 64 + w * 16 + lc;
    const unsigned short* qp = qws + (size_t)(b * SEQ + trow) * 64 + lg * 8;
    qa[0] = *(const s16x8*)(qp);
    qa[1] = *(const s16x8*)(qp + 32);
  }

  f32x4 o[4];
#pragma unroll
  for (int i = 0; i < 4; ++i) o[i] = (f32x4){0.f, 0.f, 0.f, 0.f};
  float rmax[4] = {-1e30f, -1e30f, -1e30f, -1e30f};
  float rsum[4] = {0.f, 0.f, 0.f, 0.f};

  auto issue = [&](int tile, int bi) {
#pragma unroll
    for (int p = 0; p < 2; ++p) {
      int idx = p * 256 + tid;
      int rr = idx >> 3, cc = idx & 7;
      const char* src = kbase + (size_t)(tile * 64 + rr) * 128 + ((cc ^ (rr & 7)) << 4);
      GLL16(src, &Kb[bi][(p * 256 + w * 64) * 16]);
    }
#pragma unroll
    for (int p = 0; p < 2; ++p) {
      int idx = p * 256 + tid;
      int rr = idx >> 3, cc = idx & 7;
      const char* src = vbase + (size_t)rr * (SEQ * 2) + tile * 128 + ((cc ^ (rr & 7)) << 4);
      GLL16(src, &Vb[bi][(p * 256 + w * 64) * 16]);
    }
  };

  issue(0, 0);
#pragma unroll 1
  for (int t = 0; t < SEQ / 64; ++t) {
    int bi = t & 1;
    if (t + 1 < SEQ / 64) {
      issue(t + 1, bi ^ 1);
      asm volatile("s_waitcnt vmcnt(4)" ::: "memory");  // tile t landed; t+1 in flight
    } else {
      asm volatile("s_waitcnt vmcnt(0)" ::: "memory");
    }
    __builtin_amdgcn_s_barrier();
    asm volatile("" ::: "memory");

    // QK^T: S[16 q][64 k] per wave
    f32x4 s[4];
#pragma unroll
    for (int c = 0; c < 4; ++c) {
      s[c] = (f32x4){0.f, 0.f, 0.f, 0.f};
#pragma unroll
      for (int kk = 0; kk < 2; ++kk) {
        int rowb = c * 16 + lc;
        int ch = (kk * 4 + lg) ^ (rowb & 7);
        s16x8 kf = *(const s16x8*)(&Kb[bi][rowb * 128 + ch * 16]);
        s[c] = __builtin_amdgcn_mfma_f32_16x16x32_bf16(qa[kk], kf, s[c], 0, 0, 0);
      }
    }

    // online softmax: rows live in 16-lane groups -> shfl_xor butterfly
    float al[4];
#pragma unroll
    for (int r = 0; r < 4; ++r) {
      float tm = fmaxf(fmaxf(s[0][r], s[1][r]), fmaxf(s[2][r], s[3][r]));
#pragma unroll
      for (int mk = 1; mk < 16; mk <<= 1) tm = fmaxf(tm, __shfl_xor(tm, mk, 64));
      float mn = fmaxf(rmax[r], tm);
      al[r] = __expf(rmax[r] - mn);
      rmax[r] = mn;
      float ts = 0.f;
#pragma unroll
      for (int c = 0; c < 4; ++c) {
        float p = __expf(s[c][r] - mn);
        s[c][r] = p;
        ts += p;
      }
#pragma unroll
      for (int mk = 1; mk < 16; mk <<= 1) ts += __shfl_xor(ts, mk, 64);
      rsum[r] = rsum[r] * al[r] + ts;
    }
#pragma unroll
    for (int c = 0; c < 4; ++c)
#pragma unroll
      for (int r = 0; r < 4; ++r) o[c][r] *= al[r];

    // P -> LDS (bf16), wave-private
    unsigned short* pw = (unsigned short*)Pb[w];
#pragma unroll
    for (int c = 0; c < 4; ++c)
#pragma unroll
      for (int r = 0; r < 4; ++r)
        pw[(lg * 4 + r) * 72 + c * 16 + lc] = f2bf(s[c][r]);

    // PV: O += P[16x64] * V[64x64]
#pragma unroll
    for (int kk = 0; kk < 2; ++kk) {
      s16x8 pa = *(const s16x8*)((const char*)Pb[w] + lc * 144 + kk * 64 + lg * 16);
#pragma unroll
      for (int c = 0; c < 4; ++c) {
        int rowv = c * 16 + lc;
        int ch = (kk * 4 + lg) ^ (rowv & 7);
        s16x8 vf = *(const s16x8*)(&Vb[bi][rowv * 128 + ch * 16]);
        o[c] = __builtin_amdgcn_mfma_f32_16x16x32_bf16(pa, vf, o[c], 0, 0, 0);
      }
    }
    asm volatile("" ::: "memory");
    __builtin_amdgcn_s_barrier();
  }

  // epilogue: normalize and store fp32
#pragma unroll
  for (int c = 0; c < 4; ++c) {
#pragma unroll
    for (int r = 0; r < 4; ++r) {
      int trow = qt * 64 + w * 16 + lg * 4 + r;
      out[(size_t)(b * SEQ + trow) * 64 + c * 16 + lc] = o[c][r] / rsum[r];
    }
  }
}

// ---------------------------------------------------------------------------
extern "C" void kernel_launch(void* const* d_in, const int* in_sizes, int n_in,
                              void* d_out, int out_size, void* d_ws, size_t ws_size,
                              hipStream_t stream) {
  const float* x = (const float*)d_in[0];
  const float* Wq = (const float*)d_in[1];
  const float* bq = (const float*)d_in[2];
  const float* Wk = (const float*)d_in[3];
  const float* bk = (const float*)d_in[4];
  const float* Wv = (const float*)d_in[5];
  const float* bv = (const float*)d_in[6];
  float* out = (float*)d_out;

  char* ws = (char*)d_ws;
  unsigned short* wt = (unsigned short*)(ws);             // 384 KB
  unsigned short* qws = (unsigned short*)(ws + 0x80000);  // 2 MB
  unsigned short* kws = (unsigned short*)(ws + 0x280000); // 2 MB
  unsigned short* vtws = (unsigned short*)(ws + 0x480000);// 2 MB

  k_wt<<<48, 256, 0, stream>>>(Wq, Wk, Wv, wt);
  k_proj<<<256, 256, 0, stream>>>(x, wt, bq, bk, bv, qws, kws, vtws);
  k_attn<<<dim3(64, 4), 256, 0, stream>>>(qws, kws, vtws, out);
}

// Round 2
// 107.934 us; speedup vs baseline: 1.3639x; 1.3639x over previous
//
#include <hip/hip_runtime.h>

typedef __attribute__((ext_vector_type(4))) float f32x4;
typedef __attribute__((ext_vector_type(8))) short s16x8;
typedef __attribute__((ext_vector_type(4))) short s16x4;

#define BATCH 4
#define SEQ 4096
#define EMB 1024
#define HD 64

// fp32 -> bf16 round-to-nearest-even
static __device__ __forceinline__ unsigned short f2bf(float f) {
  union { float f; unsigned int u; } a;
  a.f = f;
  unsigned int u = a.u;
  u += 0x7FFFu + ((u >> 16) & 1u);
  return (unsigned short)(u >> 16);
}

// async global->LDS, 16B per lane. dst must be wave-uniform; HW adds lane*16.
#define GLL16(g, l)                                                        \
  __builtin_amdgcn_global_load_lds(                                        \
      (const __attribute__((address_space(1))) unsigned int*)(g),          \
      (__attribute__((address_space(3))) unsigned int*)(l), 16, 0, 0)

// ---------------------------------------------------------------------------
// Kernel 1: W [1024][64] fp32 (q,k,v) -> wT [192][1024] bf16 (row = out col)
// ---------------------------------------------------------------------------
__global__ __launch_bounds__(256) void k_wt(const float* __restrict__ Wq,
                                            const float* __restrict__ Wk,
                                            const float* __restrict__ Wv,
                                            unsigned short* __restrict__ wt) {
  __shared__ float lds[64][65];
  int tid = threadIdx.x;
  int which = blockIdx.x >> 4;  // 0=q 1=k 2=v
  int kt = blockIdx.x & 15;     // 64-row k tile
  const float* W = (which == 0) ? Wq : ((which == 1) ? Wk : Wv);
#pragma unroll
  for (int i = 0; i < 4; ++i) {
    int idx = i * 256 + tid;  // 1024 float4 chunks
    int row = idx >> 4, c4 = idx & 15;
    float4 v = *(const float4*)(W + (size_t)(kt * 64 + row) * 64 + c4 * 4);
    lds[row][c4 * 4 + 0] = v.x;
    lds[row][c4 * 4 + 1] = v.y;
    lds[row][c4 * 4 + 2] = v.z;
    lds[row][c4 * 4 + 3] = v.w;
  }
  __syncthreads();
#pragma unroll
  for (int i = 0; i < 2; ++i) {
    int idx = i * 256 + tid;  // 512 chunks of 8 bf16
    int n = idx >> 3, kc = idx & 7;
    s16x8 v;
#pragma unroll
    for (int j = 0; j < 8; ++j) v[j] = (short)f2bf(lds[kc * 8 + j][n]);
    *(s16x8*)(wt + ((size_t)(which * 64 + n) * 1024 + kt * 64 + kc * 8)) = v;
  }
}

// ---------------------------------------------------------------------------
// Kernel 2: fused QKV projection. M=16384 rows, N=192 cols, K=1024.
// q scaled by 1/8 (softmax scale folded in). v written transposed [B][D][T].
// ---------------------------------------------------------------------------
__global__ __launch_bounds__(256) void k_proj(const float* __restrict__ x,
                                              const unsigned short* __restrict__ wt,
                                              const float* __restrict__ bq,
                                              const float* __restrict__ bk,
                                              const float* __restrict__ bv,
                                              unsigned short* __restrict__ qws,
                                              unsigned short* __restrict__ kws,
                                              unsigned short* __restrict__ vtws) {
  __shared__ char xb[64 * 128];   // 64 rows x 64 bf16, XOR-swizzled chunks
  __shared__ char wb[192 * 128];  // 192 cols x 64 k bf16, swizzled via source
  int tid = threadIdx.x;
  int w = tid >> 6, ln = tid & 63;
  int lg = ln >> 4, lc = ln & 15;
  int m0 = blockIdx.x * 64;

  f32x4 acc[12];
#pragma unroll
  for (int i = 0; i < 12; ++i) acc[i] = (f32x4){0.f, 0.f, 0.f, 0.f};

  for (int kt = 0; kt < 16; ++kt) {
    // stage x tile (fp32 -> bf16, swizzled ds_write)
#pragma unroll
    for (int i = 0; i < 4; ++i) {
      int idx = i * 256 + tid;  // 1024 chunks of 4 floats
      int row = idx >> 4, c4 = idx & 15;
      float4 v = *(const float4*)(x + (size_t)(m0 + row) * 1024 + kt * 64 + c4 * 4);
      s16x4 h;
      h[0] = (short)f2bf(v.x);
      h[1] = (short)f2bf(v.y);
      h[2] = (short)f2bf(v.z);
      h[3] = (short)f2bf(v.w);
      int byteoff = row * 128 + ((((c4 >> 1) ^ (row & 7)) << 4) | ((c4 & 1) << 3));
      *(s16x4*)(xb + byteoff) = h;
    }
    // stage wT tile via global_load_lds, source pre-swizzled
#pragma unroll
    for (int p = 0; p < 6; ++p) {
      int idx = p * 256 + tid;
      int rr = idx >> 3, cc = idx & 7;
      const char* src = (const char*)wt + (size_t)rr * 2048 + kt * 128 + ((cc ^ (rr & 7)) << 4);
      GLL16(src, wb + (p * 256 + w * 64) * 16);
    }
    __syncthreads();

    s16x8 a[2];
#pragma unroll
    for (int kk = 0; kk < 2; ++kk) {
      int row = w * 16 + lc;
      int ch = (kk * 4 + lg) ^ (row & 7);
      a[kk] = *(const s16x8*)(xb + row * 128 + ch * 16);
    }
#pragma unroll
    for (int cf = 0; cf < 12; ++cf) {
#pragma unroll
      for (int kk = 0; kk < 2; ++kk) {
        int rowb = cf * 16 + lc;
        int ch = (kk * 4 + lg) ^ (rowb & 7);
        s16x8 bfr = *(const s16x8*)(wb + rowb * 128 + ch * 16);
        acc[cf] = __builtin_amdgcn_mfma_f32_16x16x32_bf16(a[kk], bfr, acc[cf], 0, 0, 0);
      }
    }
    __syncthreads();
  }

  // epilogue: C layout col=lane&15, row=(lane>>4)*4+r
#pragma unroll
  for (int cf = 0; cf < 12; ++cf) {
    int dcol = (cf & 3) * 16 + lc;
    float bias = (cf < 4) ? bq[dcol] : ((cf < 8) ? bk[dcol] : bv[dcol]);
#pragma unroll
    for (int r = 0; r < 4; ++r) {
      int grow = m0 + w * 16 + lg * 4 + r;  // global row in [0,16384)
      float val = acc[cf][r] + bias;
      if (cf < 4) {
        qws[(size_t)grow * 64 + dcol] = f2bf(val * 0.125f);
      } else if (cf < 8) {
        kws[(size_t)grow * 64 + dcol] = f2bf(val);
      } else {
        int b = grow >> 12, t = grow & 4095;
        vtws[(size_t)(b * 64 + dcol) * SEQ + t] = f2bf(val);
      }
    }
  }
}

// ---------------------------------------------------------------------------
// Kernel 3: flash attention, split-KV. Block = 128 q-rows (4 waves x 32 rows),
// NS KV-splits. Writes unnormalized partial O (f32) + per-row (m,l).
// K tiles [64 k][64 d], V as Vt [64 d][64 k], XOR-swizzled LDS, double-buffered
// global_load_lds with counted vmcnt. LDS = 48KB -> 3 blocks/CU.
// ---------------------------------------------------------------------------
template <int NS>
__global__ __launch_bounds__(256, 3) void k_attn(const unsigned short* __restrict__ qws,
                                                 const unsigned short* __restrict__ kws,
                                                 const unsigned short* __restrict__ vtws,
                                                 float* __restrict__ part,
                                                 float2* __restrict__ ml) {
  __shared__ char Kb[2][8192];
  __shared__ char Vb[2][8192];
  __shared__ char Pb[4][4096];  // per-wave P: 32 rows x 64 bf16, XOR-swizzled
  int tid = threadIdx.x;
  int w = tid >> 6, ln = tid & 63;
  int lg = ln >> 4, lc = ln & 15;

  // XCD-aware remap: 32 blocks sharing (b, split) land on one XCD's L2.
  const int nb = 32 * 4 * NS;
  int L = blockIdx.x + 32 * (blockIdx.y + 4 * blockIdx.z);
  int j = (L & 7) * (nb >> 3) + (L >> 3);
  int qt = j & 31;
  int g = j >> 5;
  int b = g / NS;
  int split = g % NS;
  const int TPS = 64 / NS;  // 64-key tiles per split
  int t0 = split * TPS;

  const char* kbase = (const char*)(kws + (size_t)b * SEQ * 64);
  const char* vbase = (const char*)(vtws + (size_t)b * 64 * SEQ);

  // Q fragments: 2 sub-tiles of 16 rows (scale folded in by k_proj)
  s16x8 qa[2][2];
#pragma unroll
  for (int sub = 0; sub < 2; ++sub) {
    int trow = qt * 128 + w * 32 + sub * 16 + lc;
    const unsigned short* qp = qws + (size_t)(b * SEQ + trow) * 64 + lg * 8;
    qa[sub][0] = *(const s16x8*)(qp);
    qa[sub][1] = *(const s16x8*)(qp + 32);
  }

  f32x4 o2[2][4];
#pragma unroll
  for (int sub = 0; sub < 2; ++sub)
#pragma unroll
    for (int i = 0; i < 4; ++i) o2[sub][i] = (f32x4){0.f, 0.f, 0.f, 0.f};
  float rmax[2][4], rsum[2][4];
#pragma unroll
  for (int sub = 0; sub < 2; ++sub)
#pragma unroll
    for (int r = 0; r < 4; ++r) { rmax[sub][r] = -1e30f; rsum[sub][r] = 0.f; }

  auto issue = [&](int tile, int bi) {
#pragma unroll
    for (int p = 0; p < 2; ++p) {
      int idx = p * 256 + tid;
      int rr = idx >> 3, cc = idx & 7;
      const char* src = kbase + (size_t)(tile * 64 + rr) * 128 + ((cc ^ (rr & 7)) << 4);
      GLL16(src, &Kb[bi][(p * 256 + w * 64) * 16]);
    }
#pragma unroll
    for (int p = 0; p < 2; ++p) {
      int idx = p * 256 + tid;
      int rr = idx >> 3, cc = idx & 7;
      const char* src = vbase + (size_t)rr * (SEQ * 2) + tile * 128 + ((cc ^ (rr & 7)) << 4);
      GLL16(src, &Vb[bi][(p * 256 + w * 64) * 16]);
    }
  };

  issue(t0, 0);
#pragma unroll 1
  for (int t = 0; t < TPS; ++t) {
    int bi = t & 1;
    if (t + 1 < TPS) {
      issue(t0 + t + 1, bi ^ 1);
      asm volatile("s_waitcnt vmcnt(4)" ::: "memory");  // tile t landed; t+1 in flight
    } else {
      asm volatile("s_waitcnt vmcnt(0)" ::: "memory");
    }
    __builtin_amdgcn_s_barrier();
    asm volatile("" ::: "memory");

    // QK^T: S[32 q][64 k] per wave (K fragments shared across both q sub-tiles)
    f32x4 s[2][4];
#pragma unroll
    for (int c = 0; c < 4; ++c) {
      s[0][c] = (f32x4){0.f, 0.f, 0.f, 0.f};
      s[1][c] = (f32x4){0.f, 0.f, 0.f, 0.f};
#pragma unroll
      for (int kk = 0; kk < 2; ++kk) {
        int rowb = c * 16 + lc;
        int ch = (kk * 4 + lg) ^ (rowb & 7);
        s16x8 kf = *(const s16x8*)(&Kb[bi][rowb * 128 + ch * 16]);
        s[0][c] = __builtin_amdgcn_mfma_f32_16x16x32_bf16(qa[0][kk], kf, s[0][c], 0, 0, 0);
        s[1][c] = __builtin_amdgcn_mfma_f32_16x16x32_bf16(qa[1][kk], kf, s[1][c], 0, 0, 0);
      }
    }

    // online softmax: row-reduce over keys via 16-lane shfl butterfly
    float al[2][4];
#pragma unroll
    for (int sub = 0; sub < 2; ++sub) {
#pragma unroll
      for (int r = 0; r < 4; ++r) {
        float tm = fmaxf(fmaxf(s[sub][0][r], s[sub][1][r]), fmaxf(s[sub][2][r], s[sub][3][r]));
#pragma unroll
        for (int mk = 1; mk < 16; mk <<= 1) tm = fmaxf(tm, __shfl_xor(tm, mk, 64));
        float mn = fmaxf(rmax[sub][r], tm);
        al[sub][r] = __expf(rmax[sub][r] - mn);
        rmax[sub][r] = mn;
        float ts = 0.f;
#pragma unroll
        for (int c = 0; c < 4; ++c) {
          float p = __expf(s[sub][c][r] - mn);
          s[sub][c][r] = p;
          ts += p;
        }
#pragma unroll
        for (int mk = 1; mk < 16; mk <<= 1) ts += __shfl_xor(ts, mk, 64);
        rsum[sub][r] = rsum[sub][r] * al[sub][r] + ts;
      }
    }
#pragma unroll
    for (int sub = 0; sub < 2; ++sub)
#pragma unroll
      for (int c = 0; c < 4; ++c)
#pragma unroll
        for (int r = 0; r < 4; ++r) o2[sub][c][r] *= al[sub][r];

    // P -> LDS (bf16), wave-private, stride 64 elems + 16B-chunk XOR swizzle
#pragma unroll
    for (int sub = 0; sub < 2; ++sub)
#pragma unroll
      for (int c = 0; c < 4; ++c)
#pragma unroll
        for (int r = 0; r < 4; ++r) {
          int q = sub * 16 + lg * 4 + r;
          int ch = (c * 2 + (lc >> 3)) ^ (q & 7);
          *(unsigned short*)(Pb[w] + q * 128 + ch * 16 + (lc & 7) * 2) = f2bf(s[sub][c][r]);
        }

    // PV: O += P[32x64] * Vt (V fragments shared across both q sub-tiles)
#pragma unroll
    for (int kk = 0; kk < 2; ++kk) {
      s16x8 pa0 = *(const s16x8*)(Pb[w] + (0 * 16 + lc) * 128 + (((kk * 4 + lg) ^ (lc & 7)) << 4));
      s16x8 pa1 = *(const s16x8*)(Pb[w] + (1 * 16 + lc) * 128 + (((kk * 4 + lg) ^ (lc & 7)) << 4));
#pragma unroll
      for (int c = 0; c < 4; ++c) {
        int rowv = c * 16 + lc;
        int ch = (kk * 4 + lg) ^ (rowv & 7);
        s16x8 vf = *(const s16x8*)(&Vb[bi][rowv * 128 + ch * 16]);
        o2[0][c] = __builtin_amdgcn_mfma_f32_16x16x32_bf16(pa0, vf, o2[0][c], 0, 0, 0);
        o2[1][c] = __builtin_amdgcn_mfma_f32_16x16x32_bf16(pa1, vf, o2[1][c], 0, 0, 0);
      }
    }
    asm volatile("" ::: "memory");
    __builtin_amdgcn_s_barrier();
  }

  // epilogue: unnormalized partial O + (m, l) per row
#pragma unroll
  for (int sub = 0; sub < 2; ++sub)
#pragma unroll
    for (int c = 0; c < 4; ++c)
#pragma unroll
      for (int r = 0; r < 4; ++r) {
        int t = qt * 128 + w * 32 + sub * 16 + lg * 4 + r;
        part[((size_t)(split * 4 + b) * SEQ + t) * 64 + c * 16 + lc] = o2[sub][c][r];
      }
  if (lc == 0) {
#pragma unroll
    for (int sub = 0; sub < 2; ++sub)
#pragma unroll
      for (int r = 0; r < 4; ++r) {
        int t = qt * 128 + w * 32 + sub * 16 + lg * 4 + r;
        ml[(size_t)(split * 4 + b) * SEQ + t] = make_float2(rmax[sub][r], rsum[sub][r]);
      }
  }
}

// ---------------------------------------------------------------------------
// Kernel 4: combine KV-split partials. thread = (row, 4-col group).
// ---------------------------------------------------------------------------
template <int NS>
__global__ __launch_bounds__(256) void k_red(const float* __restrict__ part,
                                             const float2* __restrict__ ml,
                                             float* __restrict__ out) {
  int idx = blockIdx.x * 256 + threadIdx.x;  // [0, 16384*16)
  int c4 = idx & 15;
  int row = idx >> 4;  // [0, 16384) = b*4096 + t
  float2 mls[NS];
#pragma unroll
  for (int s = 0; s < NS; ++s) mls[s] = ml[(size_t)s * 16384 + row];
  float M = mls[0].x;
#pragma unroll
  for (int s = 1; s < NS; ++s) M = fmaxf(M, mls[s].x);
  float Lden = 0.f;
#pragma unroll
  for (int s = 0; s < NS; ++s) Lden += mls[s].y * __expf(mls[s].x - M);
  f32x4 acc = (f32x4){0.f, 0.f, 0.f, 0.f};
#pragma unroll
  for (int s = 0; s < NS; ++s) {
    float sc = __expf(mls[s].x - M);
    f32x4 p = *(const f32x4*)(part + ((size_t)s * 16384 + row) * 64 + c4 * 4);
#pragma unroll
    for (int i = 0; i < 4; ++i) acc[i] += sc * p[i];
  }
  float inv = 1.0f / Lden;
  f32x4 o;
#pragma unroll
  for (int i = 0; i < 4; ++i) o[i] = acc[i] * inv;
  *(f32x4*)(out + (size_t)row * 64 + c4 * 4) = o;
}

// ---------------------------------------------------------------------------
extern "C" void kernel_launch(void* const* d_in, const int* in_sizes, int n_in,
                              void* d_out, int out_size, void* d_ws, size_t ws_size,
                              hipStream_t stream) {
  const float* x = (const float*)d_in[0];
  const float* Wq = (const float*)d_in[1];
  const float* bq = (const float*)d_in[2];
  const float* Wk = (const float*)d_in[3];
  const float* bk = (const float*)d_in[4];
  const float* Wv = (const float*)d_in[5];
  const float* bv = (const float*)d_in[6];
  float* out = (float*)d_out;

  char* ws = (char*)d_ws;
  unsigned short* wt = (unsigned short*)(ws);             // 384 KB
  unsigned short* qws = (unsigned short*)(ws + 0x80000);  // 2 MB
  unsigned short* kws = (unsigned short*)(ws + 0x280000); // 2 MB
  unsigned short* vtws = (unsigned short*)(ws + 0x480000);// 2 MB
  const size_t base = 0x680000;
  const size_t perSplit = (size_t)16384 * 64 * 4 + (size_t)16384 * 8;  // part + ml

  k_wt<<<48, 256, 0, stream>>>(Wq, Wk, Wv, wt);
  k_proj<<<256, 256, 0, stream>>>(x, wt, bq, bk, bv, qws, kws, vtws);

#define RUN_NS(NSV)                                                           \
  {                                                                           \
    float* partp = (float*)(ws + base);                                       \
    float2* mlp = (float2*)(ws + base + (size_t)NSV * 16384 * 64 * 4);        \
    k_attn<NSV><<<dim3(32, 4, NSV), 256, 0, stream>>>(qws, kws, vtws, partp, mlp); \
    k_red<NSV><<<1024, 256, 0, stream>>>(partp, mlp, out);                    \
  }

  if (ws_size >= base + 8 * perSplit) {
    RUN_NS(8)
  } else if (ws_size >= base + 4 * perSplit) {
    RUN_NS(4)
  } else if (ws_size >= base + 2 * perSplit) {
    RUN_NS(2)
  } else {
    RUN_NS(1)
  }
#undef RUN_NS
}

// Round 3
// 78.379 us; speedup vs baseline: 1.8782x; 1.3771x over previous
//
#include <hip/hip_runtime.h>

typedef __attribute__((ext_vector_type(4))) float f32x4;
typedef __attribute__((ext_vector_type(16))) float f32x16;
typedef __attribute__((ext_vector_type(8))) short s16x8;
typedef __attribute__((ext_vector_type(4))) short s16x4;
typedef __attribute__((ext_vector_type(4))) unsigned u32x4;

#define BATCH 4
#define SEQ 4096
#define EMB 1024
#define HD 64
#define QSCALE (0.125f * 1.44269504088896f)  // 1/sqrt(64) * log2(e)

// fp32 -> bf16 round-to-nearest-even
static __device__ __forceinline__ unsigned short f2bf(float f) {
  union { float f; unsigned int u; } a;
  a.f = f;
  unsigned int u = a.u;
  u += 0x7FFFu + ((u >> 16) & 1u);
  return (unsigned short)(u >> 16);
}

// raw v_exp_f32: 2^x (s_nop guards raw-asm hazard window)
static __device__ __forceinline__ float fexp2(float x) {
  float r;
  asm("v_exp_f32 %0, %1\n\ts_nop 0" : "=v"(r) : "v"(x));
  return r;
}
// v_permlane32_swap_b32: a[32+i] <-> b[i]  (a keeps lo half, b keeps hi half)
static __device__ __forceinline__ void swap32f(float& a, float& b) {
  asm("s_nop 0\n\tv_permlane32_swap_b32 %0, %1\n\ts_nop 0" : "+v"(a), "+v"(b));
}
static __device__ __forceinline__ void swap32u(unsigned& a, unsigned& b) {
  asm("s_nop 0\n\tv_permlane32_swap_b32 %0, %1\n\ts_nop 0" : "+v"(a), "+v"(b));
}
static __device__ __forceinline__ unsigned cvtpk(float lo, float hi) {
  unsigned r;
  asm("v_cvt_pk_bf16_f32 %0, %1, %2" : "=v"(r) : "v"(lo), "v"(hi));
  return r;
}

// async global->LDS, 16B per lane (k_proj staging only)
#define GLL16(g, l)                                                        \
  __builtin_amdgcn_global_load_lds(                                        \
      (const __attribute__((address_space(1))) unsigned int*)(g),          \
      (__attribute__((address_space(3))) unsigned int*)(l), 16, 0, 0)

// ---------------------------------------------------------------------------
// Kernel 1: W [1024][64] fp32 (q,k,v) -> wT [192][1024] bf16 (row = out col)
// ---------------------------------------------------------------------------
__global__ __launch_bounds__(256) void k_wt(const float* __restrict__ Wq,
                                            const float* __restrict__ Wk,
                                            const float* __restrict__ Wv,
                                            unsigned short* __restrict__ wt) {
  __shared__ float lds[64][65];
  int tid = threadIdx.x;
  int which = blockIdx.x >> 4;  // 0=q 1=k 2=v
  int kt = blockIdx.x & 15;     // 64-row k tile
  const float* W = (which == 0) ? Wq : ((which == 1) ? Wk : Wv);
#pragma unroll
  for (int i = 0; i < 4; ++i) {
    int idx = i * 256 + tid;
    int row = idx >> 4, c4 = idx & 15;
    float4 v = *(const float4*)(W + (size_t)(kt * 64 + row) * 64 + c4 * 4);
    lds[row][c4 * 4 + 0] = v.x;
    lds[row][c4 * 4 + 1] = v.y;
    lds[row][c4 * 4 + 2] = v.z;
    lds[row][c4 * 4 + 3] = v.w;
  }
  __syncthreads();
#pragma unroll
  for (int i = 0; i < 2; ++i) {
    int idx = i * 256 + tid;
    int n = idx >> 3, kc = idx & 7;
    s16x8 v;
#pragma unroll
    for (int j = 0; j < 8; ++j) v[j] = (short)f2bf(lds[kc * 8 + j][n]);
    *(s16x8*)(wt + ((size_t)(which * 64 + n) * 1024 + kt * 64 + kc * 8)) = v;
  }
}

// ---------------------------------------------------------------------------
// Kernel 2: fused QKV projection. Outputs Q/K/V in MFMA-fragment layouts:
//  qfrag/kfrag (32-row tiles): b*S*64 + (t>>5)*2048 + (d>>4)*512
//                              + ((d>>3)&1)*256 + (t&31)*8 + (d&7)
//  vfrag (16-key tiles, V^T):  b*S*64 + (t>>4)*1024 + (d>>5)*512
//                              + ((t>>3)&1)*256 + (d&31)*8 + (t&7)
// q scaled by 1/8*log2e (softmax in exp2 domain).
// ---------------------------------------------------------------------------
__global__ __launch_bounds__(256) void k_proj(const float* __restrict__ x,
                                              const unsigned short* __restrict__ wt,
                                              const float* __restrict__ bq,
                                              const float* __restrict__ bk,
                                              const float* __restrict__ bv,
                                              unsigned short* __restrict__ qws,
                                              unsigned short* __restrict__ kws,
                                              unsigned short* __restrict__ vws) {
  __shared__ char xb[64 * 128];
  __shared__ char wb[192 * 128];
  int tid = threadIdx.x;
  int w = tid >> 6, ln = tid & 63;
  int lg = ln >> 4, lc = ln & 15;
  int m0 = blockIdx.x * 64;

  f32x4 acc[12];
#pragma unroll
  for (int i = 0; i < 12; ++i) acc[i] = (f32x4){0.f, 0.f, 0.f, 0.f};

  for (int kt = 0; kt < 16; ++kt) {
#pragma unroll
    for (int i = 0; i < 4; ++i) {
      int idx = i * 256 + tid;
      int row = idx >> 4, c4 = idx & 15;
      float4 v = *(const float4*)(x + (size_t)(m0 + row) * 1024 + kt * 64 + c4 * 4);
      s16x4 h;
      h[0] = (short)f2bf(v.x);
      h[1] = (short)f2bf(v.y);
      h[2] = (short)f2bf(v.z);
      h[3] = (short)f2bf(v.w);
      int byteoff = row * 128 + ((((c4 >> 1) ^ (row & 7)) << 4) | ((c4 & 1) << 3));
      *(s16x4*)(xb + byteoff) = h;
    }
#pragma unroll
    for (int p = 0; p < 6; ++p) {
      int idx = p * 256 + tid;
      int rr = idx >> 3, cc = idx & 7;
      const char* src = (const char*)wt + (size_t)rr * 2048 + kt * 128 + ((cc ^ (rr & 7)) << 4);
      GLL16(src, wb + (p * 256 + w * 64) * 16);
    }
    __syncthreads();

    s16x8 a[2];
#pragma unroll
    for (int kk = 0; kk < 2; ++kk) {
      int row = w * 16 + lc;
      int ch = (kk * 4 + lg) ^ (row & 7);
      a[kk] = *(const s16x8*)(xb + row * 128 + ch * 16);
    }
#pragma unroll
    for (int cf = 0; cf < 12; ++cf) {
#pragma unroll
      for (int kk = 0; kk < 2; ++kk) {
        int rowb = cf * 16 + lc;
        int ch = (kk * 4 + lg) ^ (rowb & 7);
        s16x8 bfr = *(const s16x8*)(wb + rowb * 128 + ch * 16);
        acc[cf] = __builtin_amdgcn_mfma_f32_16x16x32_bf16(a[kk], bfr, acc[cf], 0, 0, 0);
      }
    }
    __syncthreads();
  }

#pragma unroll
  for (int cf = 0; cf < 12; ++cf) {
    int dcol = (cf & 3) * 16 + lc;
    float bias = (cf < 4) ? bq[dcol] : ((cf < 8) ? bk[dcol] : bv[dcol]);
#pragma unroll
    for (int r = 0; r < 4; ++r) {
      int grow = m0 + w * 16 + lg * 4 + r;  // global row in [0,16384)
      int b = grow >> 12, t = grow & 4095;
      float val = acc[cf][r] + bias;
      if (cf < 4) {
        size_t off = (size_t)b * SEQ * 64 + (t >> 5) * 2048 + (dcol >> 4) * 512 +
                     ((dcol >> 3) & 1) * 256 + (t & 31) * 8 + (dcol & 7);
        qws[off] = f2bf(val * QSCALE);
      } else if (cf < 8) {
        size_t off = (size_t)b * SEQ * 64 + (t >> 5) * 2048 + (dcol >> 4) * 512 +
                     ((dcol >> 3) & 1) * 256 + (t & 31) * 8 + (dcol & 7);
        kws[off] = f2bf(val);
      } else {
        size_t off = (size_t)b * SEQ * 64 + (t >> 4) * 1024 + (dcol >> 5) * 512 +
                     ((t >> 3) & 1) * 256 + (dcol & 31) * 8 + (t & 7);
        vws[off] = f2bf(val);
      }
    }
  }
}

// ---------------------------------------------------------------------------
// Kernel 3: flash attention, 32x32 swapped-operand, LDS-free, barrier-free.
// Wave owns 64 q-rows (2 subtiles of 32). S^T = mfma(K, Q^T): col=lane&31=q,
// softmax fully in-register (permlane32_swap cross-half). P packed to bf16
// frags via cvt_pk + permlane. O accumulated transposed; partials written
// [split][b][d][T] (coalesced).
// ---------------------------------------------------------------------------
template <int NS>
__global__ __launch_bounds__(256, 2) void k_attn(const unsigned short* __restrict__ qf_g,
                                                 const unsigned short* __restrict__ kf_g,
                                                 const unsigned short* __restrict__ vf_g,
                                                 float* __restrict__ part,
                                                 float2* __restrict__ ml) {
  int tid = threadIdx.x;
  int w = tid >> 6, ln = tid & 63;
  // XCD swizzle: idx ordered split-major; XCD c gets one contiguous chunk.
  int F = blockIdx.x;
  int chunk = 8 * NS;  // (64*NS)/8
  int idx = (F & 7) * chunk + (F >> 3);
  int split = idx >> 6;
  int rem = idx & 63;
  int b = rem >> 4, q16 = rem & 15;
  const int TPS = 64 / NS;
  int t0 = split * TPS;

  const unsigned short* qb = qf_g + (size_t)b * SEQ * 64;
  const unsigned short* kb = kf_g + (size_t)b * SEQ * 64;
  const unsigned short* vb = vf_g + (size_t)b * SEQ * 64;

  int qrow = q16 * 256 + w * 64;  // wave's 64 rows within batch

  // Q fragments (stay in regs all kernel)
  s16x8 qf[2][4];
#pragma unroll
  for (int sub = 0; sub < 2; ++sub)
#pragma unroll
    for (int db = 0; db < 4; ++db)
      qf[sub][db] = *(const s16x8*)(qb + (size_t)(((q16 * 8 + w * 2 + sub) * 4 + db) * 512 + ln * 8));

  f32x16 o_[2][2];
#pragma unroll
  for (int sub = 0; sub < 2; ++sub)
#pragma unroll
    for (int dt = 0; dt < 2; ++dt)
#pragma unroll
      for (int i = 0; i < 16; ++i) o_[sub][dt][i] = 0.f;
  float m_[2] = {-1e30f, -1e30f}, l_[2] = {0.f, 0.f};

#pragma unroll 1
  for (int t = t0; t < t0 + TPS; ++t) {
    // K fragments for this 64-key tile
    s16x8 kf[2][4];
#pragma unroll
    for (int kt = 0; kt < 2; ++kt)
#pragma unroll
      for (int db = 0; db < 4; ++db)
        kf[kt][db] = *(const s16x8*)(kb + (size_t)(((t * 2 + kt) * 4 + db) * 512 + ln * 8));

    // QK^T (swapped): s_[sub][kt] = S^T[32k x 32q]
    f32x16 s_[2][2];
#pragma unroll
    for (int sub = 0; sub < 2; ++sub)
#pragma unroll
      for (int kt = 0; kt < 2; ++kt) {
        f32x16 a = {0.f, 0.f, 0.f, 0.f, 0.f, 0.f, 0.f, 0.f,
                    0.f, 0.f, 0.f, 0.f, 0.f, 0.f, 0.f, 0.f};
#pragma unroll
        for (int db = 0; db < 4; ++db)
          a = __builtin_amdgcn_mfma_f32_32x32x16_bf16(kf[kt][db], qf[sub][db], a, 0, 0, 0);
        s_[sub][kt] = a;
      }

    // V fragments (latency hides under softmax VALU)
    s16x8 vf[4][2];
#pragma unroll
    for (int k4 = 0; k4 < 4; ++k4)
#pragma unroll
      for (int dt = 0; dt < 2; ++dt)
        vf[k4][dt] = *(const s16x8*)(vb + (size_t)(((t * 4 + k4) * 2 + dt) * 512 + ln * 8));

    // softmax + pack, per sub
    s16x8 pf[2][4];
#pragma unroll
    for (int sub = 0; sub < 2; ++sub) {
      float mx[16];
#pragma unroll
      for (int i = 0; i < 16; ++i) mx[i] = fmaxf(s_[sub][0][i], s_[sub][1][i]);
#pragma unroll
      for (int i = 0; i < 8; ++i) mx[i] = fmaxf(mx[i], mx[i + 8]);
#pragma unroll
      for (int i = 0; i < 4; ++i) mx[i] = fmaxf(mx[i], mx[i + 4]);
      float tm = fmaxf(fmaxf(mx[0], mx[1]), fmaxf(mx[2], mx[3]));
      float ta = tm, tb = tm;
      swap32f(ta, tb);
      tm = fmaxf(ta, tb);
      // defer-max (T13): skip O-rescale when tile max doesn't exceed m+8
      if (!__all(tm <= m_[sub] + 8.0f)) {
        float mn = fmaxf(m_[sub], tm);
        float al = fexp2(m_[sub] - mn);
#pragma unroll
        for (int dt = 0; dt < 2; ++dt)
#pragma unroll
          for (int i = 0; i < 16; ++i) o_[sub][dt][i] *= al;
        l_[sub] *= al;
        m_[sub] = mn;
      }
      float mm = m_[sub];
#pragma unroll
      for (int kt = 0; kt < 2; ++kt)
#pragma unroll
        for (int i = 0; i < 16; ++i) s_[sub][kt][i] = fexp2(s_[sub][kt][i] - mm);
      float sm[16];
#pragma unroll
      for (int i = 0; i < 16; ++i) sm[i] = s_[sub][0][i] + s_[sub][1][i];
#pragma unroll
      for (int i = 0; i < 8; ++i) sm[i] += sm[i + 8];
#pragma unroll
      for (int i = 0; i < 4; ++i) sm[i] += sm[i + 4];
      float ts = (sm[0] + sm[1]) + (sm[2] + sm[3]);
      float sa = ts, sb = ts;
      swap32f(sa, sb);
      l_[sub] += sa + sb;
      // pack P -> bf16 frags: frag[k4] = P^T[k=16k4+8hi+j][q=lane&31]
#pragma unroll
      for (int k4 = 0; k4 < 4; ++k4) {
        int kt = k4 >> 1, mr = 2 * (k4 & 1);
        unsigned a0 = cvtpk(s_[sub][kt][mr * 4 + 0], s_[sub][kt][mr * 4 + 1]);
        unsigned a1 = cvtpk(s_[sub][kt][mr * 4 + 2], s_[sub][kt][mr * 4 + 3]);
        unsigned b0 = cvtpk(s_[sub][kt][mr * 4 + 4], s_[sub][kt][mr * 4 + 5]);
        unsigned b1 = cvtpk(s_[sub][kt][mr * 4 + 6], s_[sub][kt][mr * 4 + 7]);
        swap32u(a0, b0);
        swap32u(a1, b1);
        union { u32x4 u; s16x8 v16; } cvt;
        cvt.u = (u32x4){a0, a1, b0, b1};
        pf[sub][k4] = cvt.v16;
      }
    }

    // PV (as O^T): o_[sub][dt] += V^T-frag x P^T-frag
#pragma unroll
    for (int sub = 0; sub < 2; ++sub)
#pragma unroll
      for (int dt = 0; dt < 2; ++dt)
#pragma unroll
        for (int k4 = 0; k4 < 4; ++k4)
          o_[sub][dt] = __builtin_amdgcn_mfma_f32_32x32x16_bf16(vf[k4][dt], pf[sub][k4],
                                                                o_[sub][dt], 0, 0, 0);
  }

  // epilogue: part[(split*4+b)*64 + d][t] (coalesced: lanes = consecutive t)
  float* pb = part + (size_t)(split * 4 + b) * 64 * SEQ;
  int hi = ln >> 5, lq = ln & 31;
#pragma unroll
  for (int sub = 0; sub < 2; ++sub) {
    int tq = qrow + sub * 32 + lq;
#pragma unroll
    for (int dt = 0; dt < 2; ++dt)
#pragma unroll
      for (int re = 0; re < 16; ++re) {
        int d = dt * 32 + (re & 3) + 8 * (re >> 2) + 4 * hi;
        pb[(size_t)d * SEQ + tq] = o_[sub][dt][re];
      }
  }
  if (ln < 32) {
#pragma unroll
    for (int sub = 0; sub < 2; ++sub)
      ml[(size_t)(split * 4 + b) * SEQ + qrow + sub * 32 + ln] = make_float2(m_[0 + sub], l_[0 + sub]);
  }
}

// ---------------------------------------------------------------------------
// Kernel 4: combine KV-split partials (part layout [s][b][d][T], exp2 domain).
// Block: 16 t-rows x 64 d. Reads 64B-coalesced, writes 64B-coalesced.
// ---------------------------------------------------------------------------
template <int NS>
__global__ __launch_bounds__(256) void k_red(const float* __restrict__ part,
                                             const float2* __restrict__ ml,
                                             float* __restrict__ out) {
  int tid = threadIdx.x;
  int tg = tid & 15, dg = tid >> 4;  // t-offset, d-group(4)
  int R = blockIdx.x * 16 + tg;      // global row [0,16384)
  int b = R >> 12, t = R & 4095;
  float2 mls[NS];
#pragma unroll
  for (int s = 0; s < NS; ++s) mls[s] = ml[(size_t)(s * 4 + b) * SEQ + t];
  float M = mls[0].x;
#pragma unroll
  for (int s = 1; s < NS; ++s) M = fmaxf(M, mls[s].x);
  float Lden = 0.f;
#pragma unroll
  for (int s = 0; s < NS; ++s) Lden += mls[s].y * fexp2(mls[s].x - M);
  float acc[4] = {0.f, 0.f, 0.f, 0.f};
#pragma unroll
  for (int s = 0; s < NS; ++s) {
    float sc = fexp2(mls[s].x - M);
#pragma unroll
    for (int i = 0; i < 4; ++i)
      acc[i] += sc * part[((size_t)(s * 4 + b) * 64 + dg * 4 + i) * SEQ + t];
  }
  float inv = 1.0f / Lden;
  f32x4 o;
#pragma unroll
  for (int i = 0; i < 4; ++i) o[i] = acc[i] * inv;
  *(f32x4*)(out + (size_t)R * 64 + dg * 4) = o;
}

// ---------------------------------------------------------------------------
extern "C" void kernel_launch(void* const* d_in, const int* in_sizes, int n_in,
                              void* d_out, int out_size, void* d_ws, size_t ws_size,
                              hipStream_t stream) {
  const float* x = (const float*)d_in[0];
  const float* Wq = (const float*)d_in[1];
  const float* bq = (const float*)d_in[2];
  const float* Wk = (const float*)d_in[3];
  const float* bk = (const float*)d_in[4];
  const float* Wv = (const float*)d_in[5];
  const float* bv = (const float*)d_in[6];
  float* out = (float*)d_out;

  char* ws = (char*)d_ws;
  unsigned short* wt = (unsigned short*)(ws);             // 384 KB
  unsigned short* qws = (unsigned short*)(ws + 0x80000);  // 2 MB (qfrag)
  unsigned short* kws = (unsigned short*)(ws + 0x280000); // 2 MB (kfrag)
  unsigned short* vws = (unsigned short*)(ws + 0x480000); // 2 MB (vfrag)
  const size_t base = 0x680000;
  const size_t perSplit = (size_t)16384 * 64 * 4 + (size_t)16384 * 8;  // part + ml

  k_wt<<<48, 256, 0, stream>>>(Wq, Wk, Wv, wt);
  k_proj<<<256, 256, 0, stream>>>(x, wt, bq, bk, bv, qws, kws, vws);

#define RUN_NS(NSV)                                                           \
  {                                                                           \
    float* partp = (float*)(ws + base);                                       \
    float2* mlp = (float2*)(ws + base + (size_t)NSV * 16384 * 64 * 4);        \
    k_attn<NSV><<<64 * NSV, 256, 0, stream>>>(qws, kws, vws, partp, mlp);     \
    k_red<NSV><<<1024, 256, 0, stream>>>(partp, mlp, out);                    \
  }

  if (ws_size >= base + 8 * perSplit) {
    RUN_NS(8)
  } else if (ws_size >= base + 4 * perSplit) {
    RUN_NS(4)
  } else if (ws_size >= base + 2 * perSplit) {
    RUN_NS(2)
  } else {
    RUN_NS(1)
  }
#undef RUN_NS
}